// Round 1
// baseline (245.896 us; speedup 1.0000x reference)
//
#include <hip/hip_runtime.h>
#include <hip/hip_bf16.h>
#include <cstdint>
#include <cstddef>

// Problem constants (B=4, N=256, D=32, H=512)
#define NB 4
#define NN 256
#define DD 32
#define HH 512

typedef __attribute__((ext_vector_type(8))) short short8;   // 8 bf16 (4 VGPRs) — MFMA A/B frag
typedef __attribute__((ext_vector_type(4))) float f32x4;    // MFMA C/D frag

static __device__ __forceinline__ unsigned short f2bf(float f) {
  union { float f; unsigned u; } v; v.f = f;
  unsigned r = v.u + 0x7fffu + ((v.u >> 16) & 1u);  // RNE
  return (unsigned short)(r >> 16);
}

// ---------------------------------------------------------------------------
// prep_misc: z -> bf16 copy; W2 (512x256) -> W2T (256x512) bf16
// ---------------------------------------------------------------------------
__global__ __launch_bounds__(256) void prep_misc(const float* __restrict__ z,
                                                 const float* __restrict__ W2,
                                                 unsigned short* __restrict__ zbf,
                                                 unsigned short* __restrict__ W2T) {
  int idx = blockIdx.x * 256 + threadIdx.x;
  if (idx < NB * NN * DD) {                 // 32768
    zbf[idx] = f2bf(z[idx]);
  } else {
    int t = idx - NB * NN * DD;             // t in [0, 256*512)
    int k = t >> 9, h = t & 511;            // W2T[k][h] = W2[h][k]
    W2T[t] = f2bf(W2[h * 256 + k]);
  }
}

// ---------------------------------------------------------------------------
// prep_T: Tall[bi][h][c] = sum_a z[bi][a] * W1[(a*32+c)*512 + h]   (bf16 out)
// grid (64 h-tiles of 8, 16 bi-chunks of 64), 256 threads.
// W1 slab [a=32][h8=8][c=32] staged in LDS (layout [a][h8][c] -> conflict-free
// b32 reads, lanes walk c), z rows staged in LDS, broadcast b128 reads.
// ---------------------------------------------------------------------------
__global__ __launch_bounds__(256) void prep_T(const float* __restrict__ z,
                                              const float* __restrict__ W1,
                                              unsigned short* __restrict__ Tall) {
  __shared__ float w_s[32 * 8 * 32];   // [a][h8][c]
  __shared__ float z_s[64 * 32];       // [bi][a]
  const int tid = threadIdx.x;
  const int hbase = blockIdx.x * 8;
  const int bibase = blockIdx.y * 64;

  // Stage W1 slab: 1024 (a,c) rows x 8 contiguous h each (32B segments)
  #pragma unroll
  for (int it = 0; it < 4; ++it) {
    int p = it * 256 + tid;              // p = a*32 + c
    int a = p >> 5, c = p & 31;
    const float* src = W1 + (size_t)p * 512 + hbase;
    float4 v0 = *(const float4*)(src);
    float4 v1 = *(const float4*)(src + 4);
    w_s[(a * 8 + 0) * 32 + c] = v0.x; w_s[(a * 8 + 1) * 32 + c] = v0.y;
    w_s[(a * 8 + 2) * 32 + c] = v0.z; w_s[(a * 8 + 3) * 32 + c] = v0.w;
    w_s[(a * 8 + 4) * 32 + c] = v1.x; w_s[(a * 8 + 5) * 32 + c] = v1.y;
    w_s[(a * 8 + 6) * 32 + c] = v1.z; w_s[(a * 8 + 7) * 32 + c] = v1.w;
  }
  {
    const float4* zp = (const float4*)(z + (size_t)bibase * 32);
    float4* zd = (float4*)z_s;
    zd[tid * 2]     = zp[tid * 2];
    zd[tid * 2 + 1] = zp[tid * 2 + 1];
  }
  __syncthreads();

  const int c = tid & 31, h8 = tid >> 5;
  float wreg[32];
  #pragma unroll
  for (int a = 0; a < 32; ++a) wreg[a] = w_s[(a * 8 + h8) * 32 + c];

  for (int bi = 0; bi < 64; ++bi) {
    const float4* zr = (const float4*)(z_s + bi * 32);
    float acc = 0.f;
    #pragma unroll
    for (int q = 0; q < 8; ++q) {
      float4 zz = zr[q];
      acc += zz.x * wreg[q * 4 + 0] + zz.y * wreg[q * 4 + 1]
           + zz.z * wreg[q * 4 + 2] + zz.w * wreg[q * 4 + 3];
    }
    // out index: bi*16384 + (hbase+h8)*32 + c == bi*16384 + hbase*32 + tid (coalesced)
    Tall[(size_t)(bibase + bi) * 16384 + hbase * 32 + tid] = f2bf(acc);
  }
}

// ---------------------------------------------------------------------------
// fused: per block = one (b, i, j-tile of 64).
//   loop over 8 h-chunks of 64:
//     phase1: h1c[64j x 64h] = relu(z_j @ T_i^T + b1)   (one 16x16x32 MFMA/tile, K=32)
//             -> bf16 -> LDS h1s (A-operand layout for phase2)
//     phase2: h2[64j x 256k] += h1c @ W2[chunk]          (fp32 accum in regs)
//   epilogue: relu(h2+b2) . W3 reduced over k -> logits -> mask -> sigmoid
// LDS rows padded to 40/72 bf16 so ds_read_b128 frags are <=2-way bank aliased.
// ---------------------------------------------------------------------------
__global__ __launch_bounds__(256) void fused(const unsigned short* __restrict__ Tall,
                                             const unsigned short* __restrict__ W2T,
                                             const unsigned short* __restrict__ zbf,
                                             const float* __restrict__ b1,
                                             const float* __restrict__ b2,
                                             const float* __restrict__ W3,
                                             const float* __restrict__ b3,
                                             const float* __restrict__ motif,
                                             float* __restrict__ out) {
  __shared__ unsigned short zs[64 * 40];    // z j-tile   [j][c], pad 40
  __shared__ unsigned short ts[64 * 40];    // T chunk    [h][c], pad 40
  __shared__ unsigned short h1s[64 * 72];   // h1 chunk   [j][h], pad 72
  __shared__ unsigned short w2s[256 * 72];  // W2T chunk  [k][h], pad 72
  __shared__ float red[4 * 64];             // per-wave logit partials

  const int tid = threadIdx.x;
  const int wave = tid >> 6, lane = tid & 63;
  const int quad = lane >> 4, l16 = lane & 15;

  const int bx = blockIdx.x;
  const int jt = bx & 3;
  const int bi = bx >> 2;          // b*256 + i
  const int b = bi >> 8, i = bi & 255;
  const int jbase = jt * 64;

  // stage z tile: 64x32 bf16 = 256 chunks of 16B, contiguous in global
  {
    const uint4* src = (const uint4*)(zbf + (size_t)(b * 256 + jbase) * 32);
    int j = tid >> 2, c8 = tid & 3;
    *(uint4*)&zs[j * 40 + c8 * 8] = src[tid];
  }

  // per-lane epilogue constants: this wave owns k columns [wave*64, wave*64+64)
  float b2v[4], w3v[4];
  #pragma unroll
  for (int nt = 0; nt < 4; ++nt) {
    int k = wave * 64 + nt * 16 + l16;
    b2v[nt] = b2[k];
    w3v[nt] = W3[k];
  }

  f32x4 acc[4][4];
  #pragma unroll
  for (int mt = 0; mt < 4; ++mt)
    #pragma unroll
    for (int nt = 0; nt < 4; ++nt)
      acc[mt][nt] = (f32x4){0.f, 0.f, 0.f, 0.f};

  for (int hc = 0; hc < 8; ++hc) {
    const int hbase = hc * 64;
    // stage T chunk (64h x 32c bf16, contiguous)
    {
      const uint4* src = (const uint4*)(Tall + (size_t)bi * 16384 + hbase * 32);
      int h = tid >> 2, c8 = tid & 3;
      *(uint4*)&ts[h * 40 + c8 * 8] = src[tid];
    }
    // stage W2T chunk: 256 k-rows x 64 h (128B per row slice)
    #pragma unroll
    for (int it = 0; it < 8; ++it) {
      int id = it * 256 + tid;
      int k = id >> 3, c16 = id & 7;
      *(uint4*)&w2s[k * 72 + c16 * 8] =
          *(const uint4*)(W2T + (size_t)k * 512 + hbase + c16 * 8);
    }
    __syncthreads();

    // ---- phase 1: wave handles h columns [wave*16, wave*16+16) of this chunk
    {
      short8 bfrag = *(const short8*)&ts[(wave * 16 + l16) * 40 + quad * 8];
      float bv = b1[hbase + wave * 16 + l16];
      #pragma unroll
      for (int mt = 0; mt < 4; ++mt) {
        short8 afrag = *(const short8*)&zs[(mt * 16 + l16) * 40 + quad * 8];
        f32x4 c1 = __builtin_amdgcn_mfma_f32_16x16x32_bf16(
            afrag, bfrag, (f32x4){0.f, 0.f, 0.f, 0.f}, 0, 0, 0);
        // C/D layout: col = l16 (h), row = quad*4 + r (j)
        #pragma unroll
        for (int r = 0; r < 4; ++r) {
          float v = c1[r] + bv;
          v = v > 0.f ? v : 0.f;
          h1s[(mt * 16 + quad * 4 + r) * 72 + wave * 16 + l16] = f2bf(v);
        }
      }
    }
    __syncthreads();

    // ---- phase 2: acc[64j x 64k per wave] += h1c @ W2chunk  (K=64 -> 2 ksteps)
    #pragma unroll
    for (int ks = 0; ks < 2; ++ks) {
      short8 afr[4], bfr[4];
      #pragma unroll
      for (int mt = 0; mt < 4; ++mt)
        afr[mt] = *(const short8*)&h1s[(mt * 16 + l16) * 72 + ks * 32 + quad * 8];
      #pragma unroll
      for (int nt = 0; nt < 4; ++nt)
        bfr[nt] = *(const short8*)&w2s[(wave * 64 + nt * 16 + l16) * 72 + ks * 32 + quad * 8];
      #pragma unroll
      for (int mt = 0; mt < 4; ++mt)
        #pragma unroll
        for (int nt = 0; nt < 4; ++nt)
          acc[mt][nt] = __builtin_amdgcn_mfma_f32_16x16x32_bf16(
              afr[mt], bfr[nt], acc[mt][nt], 0, 0, 0);
    }
    __syncthreads();
  }

  // ---- epilogue: relu(h2+b2) . W3, reduce over k
  float pr[4][4];
  #pragma unroll
  for (int mt = 0; mt < 4; ++mt)
    #pragma unroll
    for (int r = 0; r < 4; ++r) {
      float s = 0.f;
      #pragma unroll
      for (int nt = 0; nt < 4; ++nt) {
        float v = acc[mt][nt][r] + b2v[nt];
        v = v > 0.f ? v : 0.f;
        s += v * w3v[nt];
      }
      pr[mt][r] = s;
    }
  // reduce across the 16 lanes of each quad (same j rows, different k cols)
  #pragma unroll
  for (int mt = 0; mt < 4; ++mt)
    #pragma unroll
    for (int r = 0; r < 4; ++r) {
      float s = pr[mt][r];
      s += __shfl_xor(s, 1);
      s += __shfl_xor(s, 2);
      s += __shfl_xor(s, 4);
      s += __shfl_xor(s, 8);
      pr[mt][r] = s;
    }
  if (l16 == 0) {
    #pragma unroll
    for (int mt = 0; mt < 4; ++mt)
      #pragma unroll
      for (int r = 0; r < 4; ++r)
        red[wave * 64 + mt * 16 + quad * 4 + r] = pr[mt][r];
  }
  __syncthreads();
  if (tid < 64) {
    int j = tid;
    float logit = red[0 * 64 + j] + red[1 * 64 + j] + red[2 * 64 + j] + red[3 * 64 + j] + b3[0];
    float mm = motif[b * 256 + i] * motif[b * 256 + jbase + j];
    logit *= mm;
    float map = 1.f / (1.f + expf(-logit));
    size_t idx = (size_t)(b * 256 + i) * 256 + jbase + j;
    out[idx] = map;                        // contact_map
    out[(size_t)NB * NN * NN + idx] = logit;  // contact_logits
  }
}

// ---------------------------------------------------------------------------
extern "C" void kernel_launch(void* const* d_in, const int* in_sizes, int n_in,
                              void* d_out, int out_size, void* d_ws, size_t ws_size,
                              hipStream_t stream) {
  const float* z     = (const float*)d_in[0];
  const float* motif = (const float*)d_in[1];
  // d_in[2] residue_mask: unused by the reference computation
  const float* W1 = (const float*)d_in[3];
  const float* b1 = (const float*)d_in[4];
  const float* W2 = (const float*)d_in[5];
  const float* b2 = (const float*)d_in[6];
  const float* W3 = (const float*)d_in[7];
  const float* b3 = (const float*)d_in[8];
  float* out = (float*)d_out;

  char* ws = (char*)d_ws;
  unsigned short* Tall = (unsigned short*)ws;                          // 1024*512*32*2 = 32 MiB
  unsigned short* W2T  = (unsigned short*)(ws + 33554432);             // 256*512*2
  unsigned short* zbf  = (unsigned short*)(ws + 33554432 + 262144);    // 32768*2

  prep_misc<<<640, 256, 0, stream>>>(z, W2, zbf, W2T);
  prep_T<<<dim3(64, 16), 256, 0, stream>>>(z, W1, Tall);
  fused<<<4096, 256, 0, stream>>>(Tall, W2T, zbf, b1, b2, W3, b3, motif, out);
}

// Round 2
// 207.561 us; speedup vs baseline: 1.1847x; 1.1847x over previous
//
#include <hip/hip_runtime.h>
#include <hip/hip_bf16.h>
#include <cstdint>
#include <cstddef>

// Problem constants (B=4, N=256, D=32, H=512)
#define NB 4
#define NN 256
#define DD 32
#define HH 512

typedef __attribute__((ext_vector_type(8))) short short8;   // 8 bf16 (4 VGPRs) — MFMA A/B frag
typedef __attribute__((ext_vector_type(4))) float f32x4;    // MFMA C/D frag

static __device__ __forceinline__ unsigned short f2bf(float f) {
  union { float f; unsigned u; } v; v.f = f;
  unsigned r = v.u + 0x7fffu + ((v.u >> 16) & 1u);  // RNE
  return (unsigned short)(r >> 16);
}
static __device__ __forceinline__ unsigned pack2bf(float lo, float hi) {
  return (unsigned)f2bf(lo) | ((unsigned)f2bf(hi) << 16);
}

// ---------------------------------------------------------------------------
// prep_misc: z -> bf16 copy; W2 (512x256 fp32) -> W2F bf16 in MFMA B-fragment
// order so the fused kernel loads B-frags as single coalesced 16B global loads:
//   W2F[(((wv*8 + hc)*4 + nt)*2 + ks)*512 + lane*8 + e] = W2[h][k]
//   h = hc*64 + ks*32 + (lane>>4)*8 + e ; k = wv*64 + nt*16 + (lane&15)
// ---------------------------------------------------------------------------
__global__ __launch_bounds__(256) void prep_misc(const float* __restrict__ z,
                                                 const float* __restrict__ W2,
                                                 unsigned short* __restrict__ zbf,
                                                 unsigned short* __restrict__ W2F) {
  int idx = blockIdx.x * 256 + threadIdx.x;
  if (idx < NB * NN * DD) {                 // 32768
    zbf[idx] = f2bf(z[idx]);
  } else {
    int t = idx - NB * NN * DD;             // t in [0, 131072)
    int e = t & 7;
    int lane = (t >> 3) & 63;
    int ks = (t >> 9) & 1;
    int nt = (t >> 10) & 3;
    int hc = (t >> 12) & 7;
    int wv = t >> 15;
    int h = hc * 64 + ks * 32 + (lane >> 4) * 8 + e;
    int k = wv * 64 + nt * 16 + (lane & 15);
    W2F[t] = f2bf(W2[h * 256 + k]);
  }
}

// ---------------------------------------------------------------------------
// prep_T: Tall[bi][h][c] = sum_a z[bi][a] * W1[(a*32+c)*512 + h]   (bf16 out)
// ---------------------------------------------------------------------------
__global__ __launch_bounds__(256) void prep_T(const float* __restrict__ z,
                                              const float* __restrict__ W1,
                                              unsigned short* __restrict__ Tall) {
  __shared__ float w_s[32 * 8 * 32];   // [a][h8][c]
  __shared__ float z_s[64 * 32];       // [bi][a]
  const int tid = threadIdx.x;
  const int hbase = blockIdx.x * 8;
  const int bibase = blockIdx.y * 64;

  #pragma unroll
  for (int it = 0; it < 4; ++it) {
    int p = it * 256 + tid;              // p = a*32 + c
    int a = p >> 5, c = p & 31;
    const float* src = W1 + (size_t)p * 512 + hbase;
    float4 v0 = *(const float4*)(src);
    float4 v1 = *(const float4*)(src + 4);
    w_s[(a * 8 + 0) * 32 + c] = v0.x; w_s[(a * 8 + 1) * 32 + c] = v0.y;
    w_s[(a * 8 + 2) * 32 + c] = v0.z; w_s[(a * 8 + 3) * 32 + c] = v0.w;
    w_s[(a * 8 + 4) * 32 + c] = v1.x; w_s[(a * 8 + 5) * 32 + c] = v1.y;
    w_s[(a * 8 + 6) * 32 + c] = v1.z; w_s[(a * 8 + 7) * 32 + c] = v1.w;
  }
  {
    const float4* zp = (const float4*)(z + (size_t)bibase * 32);
    float4* zd = (float4*)z_s;
    zd[tid * 2]     = zp[tid * 2];
    zd[tid * 2 + 1] = zp[tid * 2 + 1];
  }
  __syncthreads();

  const int c = tid & 31, h8 = tid >> 5;
  float wreg[32];
  #pragma unroll
  for (int a = 0; a < 32; ++a) wreg[a] = w_s[(a * 8 + h8) * 32 + c];

  for (int bi = 0; bi < 64; ++bi) {
    const float4* zr = (const float4*)(z_s + bi * 32);
    float acc = 0.f;
    #pragma unroll
    for (int q = 0; q < 8; ++q) {
      float4 zz = zr[q];
      acc += zz.x * wreg[q * 4 + 0] + zz.y * wreg[q * 4 + 1]
           + zz.z * wreg[q * 4 + 2] + zz.w * wreg[q * 4 + 3];
    }
    Tall[(size_t)(bibase + bi) * 16384 + hbase * 32 + tid] = f2bf(acc);
  }
}

// ---------------------------------------------------------------------------
// fused: per block = one (b, i, j-tile of 64). LDS holds ONLY the h1 chunk
// (double-buffered) — z/T/W2 fragments come straight from global (L2-hot,
// per-lane-contiguous 16B loads). One barrier per h-chunk.
//
//   phase1(hc): h1[h=64][j=64] = relu(T_i z_j^T + b1) via mfma(tfr, zfr)
//               (D row = h → 4 consecutive h per lane → one ds_write_b64)
//   phase2(hc): acc[64j x 64k/wave] += h1 @ W2  via mfma(afr, bfr)
//   epilogue:   relu(acc + b2) . W3 reduced over k → mask → sigmoid
// ---------------------------------------------------------------------------
__global__ __launch_bounds__(256) void fused(const unsigned short* __restrict__ Tall,
                                             const unsigned short* __restrict__ W2F,
                                             const unsigned short* __restrict__ zbf,
                                             const float* __restrict__ b1,
                                             const float* __restrict__ b2,
                                             const float* __restrict__ W3,
                                             const float* __restrict__ b3,
                                             const float* __restrict__ motif,
                                             float* __restrict__ out) {
  __shared__ unsigned short h1s[2][64 * 72];   // [j][h], pad 72 (stride ≡ 4 banks)
  __shared__ float red[4 * 64];

  const int tid = threadIdx.x;
  const int wave = tid >> 6, lane = tid & 63;
  const int quad = lane >> 4, l16 = lane & 15;

  const int bx = blockIdx.x;
  const int jt = bx & 3;
  const int bi = bx >> 2;          // b*256 + i
  const int b = bi >> 8, i = bi & 255;
  const int jbase = jt * 64;

  // z fragments (phase-1 B operand), hc-invariant: hoisted to registers.
  // zfr[nt][e] = z[b][jbase + nt*16 + l16][quad*8 + e]
  short8 zfr[4];
  #pragma unroll
  for (int nt = 0; nt < 4; ++nt)
    zfr[nt] = *(const short8*)(zbf + (size_t)(b * 256 + jbase + nt * 16 + l16) * 32 + quad * 8);

  // epilogue constants: this wave owns k in [wave*64, wave*64+64)
  float b2v[4], w3v[4];
  #pragma unroll
  for (int nt = 0; nt < 4; ++nt) {
    int k = wave * 64 + nt * 16 + l16;
    b2v[nt] = b2[k];
    w3v[nt] = W3[k];
  }

  f32x4 acc[4][4];
  #pragma unroll
  for (int mt = 0; mt < 4; ++mt)
    #pragma unroll
    for (int nt = 0; nt < 4; ++nt)
      acc[mt][nt] = (f32x4){0.f, 0.f, 0.f, 0.f};

  // per-lane global bases
  const unsigned short* Tbase = Tall + (size_t)bi * 16384 + (wave * 16 + l16) * 32 + quad * 8;
  const unsigned short* Wbase = W2F + (size_t)wave * 8 * 4096 + lane * 8;
  const float* b1base = b1 + wave * 16 + quad * 4;

  // phase1(hc): compute h1 chunk hc into h1s[buf]
  auto phase1 = [&](int hc, int buf) {
    short8 tfr = *(const short8*)(Tbase + hc * 64 * 32);
    float4 b1f = *(const float4*)(b1base + hc * 64);
    #pragma unroll
    for (int nt = 0; nt < 4; ++nt) {
      f32x4 c1 = __builtin_amdgcn_mfma_f32_16x16x32_bf16(
          tfr, zfr[nt], (f32x4){0.f, 0.f, 0.f, 0.f}, 0, 0, 0);
      // D: row = quad*4+r -> h (within wave's 16), col = l16 -> j (within nt's 16)
      float v0 = fmaxf(c1[0] + b1f.x, 0.f);
      float v1 = fmaxf(c1[1] + b1f.y, 0.f);
      float v2 = fmaxf(c1[2] + b1f.z, 0.f);
      float v3 = fmaxf(c1[3] + b1f.w, 0.f);
      uint2 p;
      p.x = pack2bf(v0, v1);
      p.y = pack2bf(v2, v3);
      *(uint2*)&h1s[buf][(nt * 16 + l16) * 72 + wave * 16 + quad * 4] = p;
    }
  };

  // phase2(hc): accumulate h1(chunk hc) @ W2(chunk hc)
  auto phase2 = [&](int hc, int buf) {
    short8 bfr[8];
    #pragma unroll
    for (int f = 0; f < 8; ++f)          // f = nt*2 + ks
      bfr[f] = *(const short8*)(Wbase + (size_t)hc * 4096 + f * 512);
    #pragma unroll
    for (int ks = 0; ks < 2; ++ks) {
      short8 afr[4];
      #pragma unroll
      for (int mt = 0; mt < 4; ++mt)
        afr[mt] = *(const short8*)&h1s[buf][(mt * 16 + l16) * 72 + ks * 32 + quad * 8];
      #pragma unroll
      for (int mt = 0; mt < 4; ++mt)
        #pragma unroll
        for (int nt = 0; nt < 4; ++nt)
          acc[mt][nt] = __builtin_amdgcn_mfma_f32_16x16x32_bf16(
              afr[mt], bfr[nt * 2 + ks], acc[mt][nt], 0, 0, 0);
    }
  };

  phase1(0, 0);
  __syncthreads();
  for (int hc = 0; hc < 8; ++hc) {
    if (hc < 7) phase1(hc + 1, (hc + 1) & 1);
    phase2(hc, hc & 1);
    __syncthreads();
  }

  // ---- epilogue: relu(h2+b2) . W3, reduce over k
  float pr[4][4];
  #pragma unroll
  for (int mt = 0; mt < 4; ++mt)
    #pragma unroll
    for (int r = 0; r < 4; ++r) {
      float s = 0.f;
      #pragma unroll
      for (int nt = 0; nt < 4; ++nt) {
        float v = acc[mt][nt][r] + b2v[nt];
        v = v > 0.f ? v : 0.f;
        s += v * w3v[nt];
      }
      pr[mt][r] = s;
    }
  #pragma unroll
  for (int mt = 0; mt < 4; ++mt)
    #pragma unroll
    for (int r = 0; r < 4; ++r) {
      float s = pr[mt][r];
      s += __shfl_xor(s, 1);
      s += __shfl_xor(s, 2);
      s += __shfl_xor(s, 4);
      s += __shfl_xor(s, 8);
      pr[mt][r] = s;
    }
  if (l16 == 0) {
    #pragma unroll
    for (int mt = 0; mt < 4; ++mt)
      #pragma unroll
      for (int r = 0; r < 4; ++r)
        red[wave * 64 + mt * 16 + quad * 4 + r] = pr[mt][r];
  }
  __syncthreads();
  if (tid < 64) {
    int j = tid;
    float logit = red[0 * 64 + j] + red[1 * 64 + j] + red[2 * 64 + j] + red[3 * 64 + j] + b3[0];
    float mm = motif[b * 256 + i] * motif[b * 256 + jbase + j];
    logit *= mm;
    float map = 1.f / (1.f + expf(-logit));
    size_t idx = (size_t)(b * 256 + i) * 256 + jbase + j;
    out[idx] = map;                           // contact_map
    out[(size_t)NB * NN * NN + idx] = logit;  // contact_logits
  }
}

// ---------------------------------------------------------------------------
extern "C" void kernel_launch(void* const* d_in, const int* in_sizes, int n_in,
                              void* d_out, int out_size, void* d_ws, size_t ws_size,
                              hipStream_t stream) {
  const float* z     = (const float*)d_in[0];
  const float* motif = (const float*)d_in[1];
  // d_in[2] residue_mask: all-ones, unused by the reference computation
  const float* W1 = (const float*)d_in[3];
  const float* b1 = (const float*)d_in[4];
  const float* W2 = (const float*)d_in[5];
  const float* b2 = (const float*)d_in[6];
  const float* W3 = (const float*)d_in[7];
  const float* b3 = (const float*)d_in[8];
  float* out = (float*)d_out;

  char* ws = (char*)d_ws;
  unsigned short* Tall = (unsigned short*)ws;                          // 1024*512*32*2 = 32 MiB
  unsigned short* W2F  = (unsigned short*)(ws + 33554432);             // 131072*2 = 256 KiB
  unsigned short* zbf  = (unsigned short*)(ws + 33554432 + 262144);    // 32768*2

  prep_misc<<<640, 256, 0, stream>>>(z, W2, zbf, W2F);
  prep_T<<<dim3(64, 16), 256, 0, stream>>>(z, W1, Tall);
  fused<<<4096, 256, 0, stream>>>(Tall, W2F, zbf, b1, b2, W3, b3, motif, out);
}

// Round 3
// 191.304 us; speedup vs baseline: 1.2854x; 1.0850x over previous
//
#include <hip/hip_runtime.h>
#include <hip/hip_bf16.h>
#include <cstdint>
#include <cstddef>

// Problem constants (B=4, N=256, D=32, H=512)
#define NB 4
#define NN 256
#define DD 32
#define HH 512

typedef __attribute__((ext_vector_type(8))) short short8;   // 8 bf16 (4 VGPRs) — MFMA A/B frag
typedef __attribute__((ext_vector_type(4))) float f32x4;    // MFMA C/D frag

// HW packed fp32->bf16 (RNE). a -> low 16, b -> high 16.
static __device__ __forceinline__ unsigned cvtpk(float a, float b) {
  unsigned r;
  asm("v_cvt_pk_bf16_f32 %0, %1, %2" : "=v"(r) : "v"(a), "v"(b));
  return r;
}
static __device__ __forceinline__ unsigned short f2bf1(float a) {
  return (unsigned short)(cvtpk(a, 0.f) & 0xffffu);
}

// ---------------------------------------------------------------------------
// prep_all (grid 384x256): three regions by thread id.
//  A: t in [0,16384):       zbf (bf16 copy of z), 2 elems/thread
//  B: t in [16384,32768):   W2F — W2 (512x256) in MFMA B-frag order:
//       W2F[(((wv*8+hc)*4+nt)*2+ks)*64 + lane][e] = W2[h][k]
//       h = hc*64+ks*32+(lane>>4)*8+e ; k = wv*64+nt*16+(lane&15)
//  C: t in [32768,98304):   W1F — W1 permuted into B-frag order for prep_T2:
//       W1F[(n>>4)*512 + (a>>3)*128 + (n&15)*8 + (a&7)] = W1[(a*32+(n&31))*512 + (n>>5)]
// ---------------------------------------------------------------------------
__global__ __launch_bounds__(256) void prep_all(const float* __restrict__ z,
                                                const float* __restrict__ W1,
                                                const float* __restrict__ W2,
                                                unsigned short* __restrict__ zbf,
                                                unsigned short* __restrict__ W2F,
                                                unsigned short* __restrict__ W1F) {
  int t = blockIdx.x * 256 + threadIdx.x;
  if (t < 16384) {
    float2 v = ((const float2*)z)[t];
    ((unsigned*)zbf)[t] = cvtpk(v.x, v.y);
  } else if (t < 32768) {
    int f8 = t - 16384;                   // frag-slot index (8 elems each)
    int lane = f8 & 63;
    int ks = (f8 >> 6) & 1, nt = (f8 >> 7) & 3, hc = (f8 >> 9) & 7, wv = f8 >> 12;
    int k = wv * 64 + nt * 16 + (lane & 15);
    int hb = hc * 64 + ks * 32 + (lane >> 4) * 8;
    float v[8];
    #pragma unroll
    for (int e = 0; e < 8; ++e) v[e] = W2[(hb + e) * 256 + k];
    uint4 p;
    p.x = cvtpk(v[0], v[1]); p.y = cvtpk(v[2], v[3]);
    p.z = cvtpk(v[4], v[5]); p.w = cvtpk(v[6], v[7]);
    ((uint4*)W2F)[f8] = p;
  } else {
    int g = t - 32768;                    // [0, 65536)
    int n = ((g >> 6) << 4) | (g & 15);   // n = h*32 + c, the output column
    int quad = (g >> 4) & 3;
    int c = n & 31, h = n >> 5;
    float v[8];
    #pragma unroll
    for (int e = 0; e < 8; ++e) {
      int a = quad * 8 + e;
      v[e] = W1[(a * 32 + c) * 512 + h];
    }
    uint4 p;
    p.x = cvtpk(v[0], v[1]); p.y = cvtpk(v[2], v[3]);
    p.z = cvtpk(v[4], v[5]); p.w = cvtpk(v[6], v[7]);
    ((uint4*)W1F)[g] = p;
  }
}

// ---------------------------------------------------------------------------
// prep_T2: Tall[bi][n] = sum_a z[bi][a] * W1p[a][n]  as MFMA GEMM
//   M=1024 (bi), N=16384 (n=h*32+c), K=32 (a). grid (64 n-blocks x 16 m-blocks).
//   Block: 64 bi x 256 n; wave w owns n-range [nblk*256+w*64, +64).
//   No LDS, no barrier: A/B frags are per-lane-contiguous 16B global loads.
// ---------------------------------------------------------------------------
__global__ __launch_bounds__(256) void prep_T2(const unsigned short* __restrict__ zbf,
                                               const unsigned short* __restrict__ W1F,
                                               unsigned short* __restrict__ Tall) {
  const int tid = threadIdx.x;
  const int w = tid >> 6, lane = tid & 63;
  const int quad = lane >> 4, l16 = lane & 15;
  const int nblk = blockIdx.x, mblk = blockIdx.y;
  const int bibase = mblk * 64;

  short8 afr[4], bfr[4];
  #pragma unroll
  for (int mt = 0; mt < 4; ++mt)
    afr[mt] = *(const short8*)(zbf + (size_t)(bibase + mt * 16 + l16) * 32 + quad * 8);
  #pragma unroll
  for (int nt = 0; nt < 4; ++nt)
    bfr[nt] = *(const short8*)(W1F + (size_t)(nblk * 16 + w * 4 + nt) * 512 + lane * 8);

  f32x4 d[4][4];
  #pragma unroll
  for (int mt = 0; mt < 4; ++mt)
    #pragma unroll
    for (int nt = 0; nt < 4; ++nt)
      d[mt][nt] = __builtin_amdgcn_mfma_f32_16x16x32_bf16(
          afr[mt], bfr[nt], (f32x4){0.f, 0.f, 0.f, 0.f}, 0, 0, 0);

  // D: row(m=bi) = quad*4+r, col(n) = l16
  const int ncol = nblk * 256 + w * 64;
  #pragma unroll
  for (int mt = 0; mt < 4; ++mt)
    #pragma unroll
    for (int r = 0; r < 4; ++r) {
      size_t rowoff = (size_t)(bibase + mt * 16 + quad * 4 + r) * 16384;
      #pragma unroll
      for (int nt = 0; nt < 4; ++nt)
        Tall[rowoff + ncol + nt * 16 + l16] = f2bf1(d[mt][nt][r]);
    }
}

// ---------------------------------------------------------------------------
// fused: per block = one (b, i, j-tile of 64). LDS: double-buffered h1 chunk.
// Software-pipelined: next-hc tfr/b1/ks0-W2F frags prefetched before current
// phase-2 MFMA block; ks1 frags loaded before ks0 MFMAs. One barrier per hc.
// ---------------------------------------------------------------------------
__global__ __launch_bounds__(256) void fused(const unsigned short* __restrict__ Tall,
                                             const unsigned short* __restrict__ W2F,
                                             const unsigned short* __restrict__ zbf,
                                             const float* __restrict__ b1,
                                             const float* __restrict__ b2,
                                             const float* __restrict__ W3,
                                             const float* __restrict__ b3,
                                             const float* __restrict__ motif,
                                             float* __restrict__ out) {
  __shared__ unsigned short h1s[2][64 * 72];   // [j][h], pad 72
  __shared__ float red[4 * 64];

  const int tid = threadIdx.x;
  const int wave = tid >> 6, lane = tid & 63;
  const int quad = lane >> 4, l16 = lane & 15;

  const int bx = blockIdx.x;
  const int jt = bx & 3;
  const int bi = bx >> 2;          // b*256 + i
  const int b = bi >> 8, i = bi & 255;
  const int jbase = jt * 64;

  // z fragments (phase-1 B operand), hc-invariant
  short8 zfr[4];
  #pragma unroll
  for (int nt = 0; nt < 4; ++nt)
    zfr[nt] = *(const short8*)(zbf + (size_t)(b * 256 + jbase + nt * 16 + l16) * 32 + quad * 8);

  // epilogue constants: this wave owns k in [wave*64, wave*64+64)
  float b2v[4], w3v[4];
  #pragma unroll
  for (int nt = 0; nt < 4; ++nt) {
    int k = wave * 64 + nt * 16 + l16;
    b2v[nt] = b2[k];
    w3v[nt] = W3[k];
  }

  f32x4 acc[4][4];
  #pragma unroll
  for (int mt = 0; mt < 4; ++mt)
    #pragma unroll
    for (int nt = 0; nt < 4; ++nt)
      acc[mt][nt] = (f32x4){0.f, 0.f, 0.f, 0.f};

  const unsigned short* Tbase = Tall + (size_t)bi * 16384 + (wave * 16 + l16) * 32 + quad * 8;
  const unsigned short* Wbase = W2F + (size_t)wave * 32768 + lane * 8;
  const float* b1base = b1 + wave * 16 + quad * 4;

  // phase1: h1[h][j] = relu(T z^T + b1) -> bf16 -> h1s[buf]
  auto phase1 = [&](short8 tfr, float4 b1f, int buf) {
    #pragma unroll
    for (int nt = 0; nt < 4; ++nt) {
      f32x4 c1 = __builtin_amdgcn_mfma_f32_16x16x32_bf16(
          tfr, zfr[nt], (f32x4){0.f, 0.f, 0.f, 0.f}, 0, 0, 0);
      float v0 = fmaxf(c1[0] + b1f.x, 0.f);
      float v1 = fmaxf(c1[1] + b1f.y, 0.f);
      float v2 = fmaxf(c1[2] + b1f.z, 0.f);
      float v3 = fmaxf(c1[3] + b1f.w, 0.f);
      uint2 p;
      p.x = cvtpk(v0, v1);
      p.y = cvtpk(v2, v3);
      *(uint2*)&h1s[buf][(nt * 16 + l16) * 72 + wave * 16 + quad * 4] = p;
    }
  };

  // prologue: hc = 0 frags
  short8 tfr0 = *(const short8*)(Tbase);
  float4 b1f0 = *(const float4*)(b1base);
  short8 bfrA[4];                        // ks=0 frags of current hc
  #pragma unroll
  for (int nt = 0; nt < 4; ++nt)
    bfrA[nt] = *(const short8*)(Wbase + nt * 2 * 512);
  phase1(tfr0, b1f0, 0);
  __syncthreads();

  for (int hc = 0; hc < 8; ++hc) {
    const int buf = hc & 1;
    // ks=1 frags of current hc (consumed after ks0 MFMAs -> latency hidden)
    short8 bfrB[4];
    #pragma unroll
    for (int nt = 0; nt < 4; ++nt)
      bfrB[nt] = *(const short8*)(Wbase + (size_t)hc * 4096 + (nt * 2 + 1) * 512);

    // afr ks0 LDS reads
    short8 afr[4];
    #pragma unroll
    for (int mt = 0; mt < 4; ++mt)
      afr[mt] = *(const short8*)&h1s[buf][(mt * 16 + l16) * 72 + quad * 8];

    // prefetch next hc (completes during the 32 MFMAs below)
    short8 tfr_n; float4 b1f_n; short8 bfrA_n[4];
    if (hc < 7) {
      tfr_n = *(const short8*)(Tbase + (hc + 1) * 2048);
      b1f_n = *(const float4*)(b1base + (hc + 1) * 64);
      #pragma unroll
      for (int nt = 0; nt < 4; ++nt)
        bfrA_n[nt] = *(const short8*)(Wbase + (size_t)(hc + 1) * 4096 + nt * 2 * 512);
    }

    // ks0 MFMAs
    #pragma unroll
    for (int mt = 0; mt < 4; ++mt)
      #pragma unroll
      for (int nt = 0; nt < 4; ++nt)
        acc[mt][nt] = __builtin_amdgcn_mfma_f32_16x16x32_bf16(
            afr[mt], bfrA[nt], acc[mt][nt], 0, 0, 0);

    // afr ks1 reads + ks1 MFMAs
    #pragma unroll
    for (int mt = 0; mt < 4; ++mt)
      afr[mt] = *(const short8*)&h1s[buf][(mt * 16 + l16) * 72 + 32 + quad * 8];
    #pragma unroll
    for (int mt = 0; mt < 4; ++mt)
      #pragma unroll
      for (int nt = 0; nt < 4; ++nt)
        acc[mt][nt] = __builtin_amdgcn_mfma_f32_16x16x32_bf16(
            afr[mt], bfrB[nt], acc[mt][nt], 0, 0, 0);

    if (hc < 7) {
      phase1(tfr_n, b1f_n, buf ^ 1);
      #pragma unroll
      for (int nt = 0; nt < 4; ++nt) bfrA[nt] = bfrA_n[nt];
    }
    __syncthreads();
  }

  // ---- epilogue: relu(h2+b2) . W3, reduce over k
  float pr[4][4];
  #pragma unroll
  for (int mt = 0; mt < 4; ++mt)
    #pragma unroll
    for (int r = 0; r < 4; ++r) {
      float s = 0.f;
      #pragma unroll
      for (int nt = 0; nt < 4; ++nt) {
        float v = acc[mt][nt][r] + b2v[nt];
        v = v > 0.f ? v : 0.f;
        s += v * w3v[nt];
      }
      pr[mt][r] = s;
    }
  #pragma unroll
  for (int mt = 0; mt < 4; ++mt)
    #pragma unroll
    for (int r = 0; r < 4; ++r) {
      float s = pr[mt][r];
      s += __shfl_xor(s, 1);
      s += __shfl_xor(s, 2);
      s += __shfl_xor(s, 4);
      s += __shfl_xor(s, 8);
      pr[mt][r] = s;
    }
  if (l16 == 0) {
    #pragma unroll
    for (int mt = 0; mt < 4; ++mt)
      #pragma unroll
      for (int r = 0; r < 4; ++r)
        red[wave * 64 + mt * 16 + quad * 4 + r] = pr[mt][r];
  }
  __syncthreads();
  if (tid < 64) {
    int j = tid;
    float logit = red[0 * 64 + j] + red[1 * 64 + j] + red[2 * 64 + j] + red[3 * 64 + j] + b3[0];
    float mm = motif[b * 256 + i] * motif[b * 256 + jbase + j];
    logit *= mm;
    float map = 1.f / (1.f + expf(-logit));
    size_t idx = (size_t)(b * 256 + i) * 256 + jbase + j;
    out[idx] = map;                           // contact_map
    out[(size_t)NB * NN * NN + idx] = logit;  // contact_logits
  }
}

// ---------------------------------------------------------------------------
extern "C" void kernel_launch(void* const* d_in, const int* in_sizes, int n_in,
                              void* d_out, int out_size, void* d_ws, size_t ws_size,
                              hipStream_t stream) {
  const float* z     = (const float*)d_in[0];
  const float* motif = (const float*)d_in[1];
  // d_in[2] residue_mask: all-ones, unused by the reference computation
  const float* W1 = (const float*)d_in[3];
  const float* b1 = (const float*)d_in[4];
  const float* W2 = (const float*)d_in[5];
  const float* b2 = (const float*)d_in[6];
  const float* W3 = (const float*)d_in[7];
  const float* b3 = (const float*)d_in[8];
  float* out = (float*)d_out;

  char* ws = (char*)d_ws;
  unsigned short* Tall = (unsigned short*)ws;                       // 32 MiB
  unsigned short* W2F  = (unsigned short*)(ws + 33554432);          // 256 KiB
  unsigned short* zbf  = (unsigned short*)(ws + 33554432 + 262144); // 64 KiB
  unsigned short* W1F  = (unsigned short*)(ws + 33554432 + 262144 + 65536); // 1 MiB

  prep_all<<<384, 256, 0, stream>>>(z, W1, W2, zbf, W2F, W1F);
  prep_T2<<<dim3(64, 16), 256, 0, stream>>>(zbf, W1F, Tall);
  fused<<<4096, 256, 0, stream>>>(Tall, W2F, zbf, b1, b2, W3, b3, motif, out);
}